// Round 8
// baseline (13.340 us; speedup 1.0000x reference)
//
#include <hip/hip_runtime.h>

// Soft-DTW (banded, r1=BIG, R0 finite only at j=0) collapses exactly to the
// diagonal distance sum: out = sum_i sqrt(max(||x_i - y_i||^2, 1e-12)).
//
// Single kernel node. Combine protocol: ONE relaxed u64 atomicAdd per block,
//   addend = (fixed_point_partial << 32) | 1.
// Low word counts blocks (< 2^32/..., never carries); high word accumulates
// the 2^-14 fixed-point sum (<= ~1.5e9 < 2^32). Block seeing old-count ==
// NBLK-1 holds the full sum in the RETURN VALUE -> writes out, resets.
// Bitwise-deterministic (integer adds commute). Poison/init: low32 >= NBLK
// -> full-word-expected CAS normalize (any concurrent add invalidates a
// stale CAS -> race-free by construction).
//
// R3: memset node +13us. R4: grid.sync +27us. R6->7: fused atomic -11%.
// R8 experiment: 512 blocks / 2 rows per wave (2 blocks/CU, half the
// per-wave serial work) to test kernel-latency vs launch-overhead floor.

#define TN 4096
#define DFN 256
#define RPB 8
#define NBLK (TN / RPB)  // 512 blocks, 4 waves, 2 rows/wave
#define FXS 16384.0f     // 2^14 fixed-point scale

#define AGENT __HIP_MEMORY_SCOPE_AGENT

__global__ __launch_bounds__(256) void sdtw_one(const float* __restrict__ x,
                                                const float* __restrict__ y,
                                                unsigned long long* __restrict__ acc,
                                                float* __restrict__ out) {
  const int wave = threadIdx.x >> 6;
  const int lane = threadIdx.x & 63;
  __shared__ float wsum[4];

  // Early probe (off the tail critical path). Steady state: low32 < NBLK.
  unsigned long long v0 = 0;
  if (threadIdx.x == 0) v0 = __hip_atomic_load(acc, __ATOMIC_RELAXED, AGENT);

  // --- per-block diagonal partial: RPB rows, 2 per wave ---
  const int base = blockIdx.x * RPB + wave * 2;
  float d2[2];
#pragma unroll
  for (int r = 0; r < 2; ++r) {
    const float4 xv =
        reinterpret_cast<const float4*>(x)[(base + r) * (DFN / 4) + lane];
    const float4 yv =
        reinterpret_cast<const float4*>(y)[(base + r) * (DFN / 4) + lane];
    const float a = xv.x - yv.x;
    const float b = xv.y - yv.y;
    const float c = xv.z - yv.z;
    const float d = xv.w - yv.w;
    d2[r] = a * a + b * b + c * c + d * d;
  }
  float pacc = 0.0f;
#pragma unroll
  for (int r = 0; r < 2; ++r) {
    float v = d2[r];
#pragma unroll
    for (int s = 32; s >= 1; s >>= 1) v += __shfl_xor(v, s, 64);
    pacc += sqrtf(fmaxf(v, 1e-12f));
  }
  if (lane == 0) wsum[wave] = pacc;
  __syncthreads();

  if (threadIdx.x == 0) {
    const float p = (wsum[0] + wsum[1]) + (wsum[2] + wsum[3]);

    // Init-agnostic normalize; fast path costs nothing (v0 in register).
    unsigned long long v = v0;
    while ((unsigned)(v & 0xFFFFFFFFull) >= (unsigned)NBLK) {
      if (__hip_atomic_compare_exchange_strong(acc, &v, 0ull, __ATOMIC_RELAXED,
                                               __ATOMIC_RELAXED, AGENT))
        break;
    }

    const unsigned long long fx = (unsigned long long)(unsigned)(p * FXS + 0.5f);
    const unsigned long long add = (fx << 32) | 1ull;
    const unsigned long long old =
        __hip_atomic_fetch_add(acc, add, __ATOMIC_RELAXED, AGENT);

    if ((unsigned)(old & 0xFFFFFFFFull) == (unsigned)(NBLK - 1)) {
      const unsigned long long tot = (old >> 32) + fx;
      out[0] = (float)tot * (1.0f / FXS);
      __hip_atomic_store(acc, 0ull, __ATOMIC_RELAXED, AGENT);
    }
  }
}

extern "C" void kernel_launch(void* const* d_in, const int* in_sizes, int n_in,
                              void* d_out, int out_size, void* d_ws,
                              size_t ws_size, hipStream_t stream) {
  const float* x = (const float*)d_in[0];
  const float* y = (const float*)d_in[1];
  unsigned long long* acc = (unsigned long long*)d_ws;  // 8 bytes, aligned
  float* out = (float*)d_out;

  sdtw_one<<<NBLK, 256, 0, stream>>>(x, y, acc, out);
}